// Round 20
// baseline (182.435 us; speedup 1.0000x reference)
//
#include <hip/hip_runtime.h>
#include <cstddef>

#define NN 50000
#define NPAD 50048            // 782 blocks * 64 rows
#define NE 800000
#define HC 128
#define OC 64
#define NL 3
#define BN_EPS 1e-5f
#define NB ((NN + 1023) / 1024)
#define CONVT (NN * 32)       // conv threads in prep0
#define ECAP 1250000          // padded CSR capacity (NE + 8*NN > upper bound), mult of 8
#define GEMMB 782             // gemm blocks (NPAD/64)
#define EBLK 3125             // edge blocks (NE/256)

typedef _Float16 half8 __attribute__((ext_vector_type(8)));
typedef _Float16 half4 __attribute__((ext_vector_type(4)));
typedef float f32x4 __attribute__((ext_vector_type(4)));
typedef unsigned short ushort4v __attribute__((ext_vector_type(4)));

// ---------------- prep0: csr pad fill + cnt zero + x conv + weight pack + BN fold + zero-row ----------------
__global__ void prep0(const float* __restrict__ x, _Float16* __restrict__ xblk,
                      const float* __restrict__ Wg, const float* __restrict__ Wl,
                      const float* __restrict__ Wp,
                      const float* __restrict__ bg, const float* __restrict__ bl,
                      const float* __restrict__ bn_g, const float* __restrict__ bn_b,
                      const float* __restrict__ bn_rm, const float* __restrict__ bn_rv,
                      _Float16* __restrict__ wgl16,   // [3][2][2048][8]
                      _Float16* __restrict__ wpp16,   // [1024][8]
                      float* __restrict__ bsum,       // [3][128]
                      float* __restrict__ bnsc, float* __restrict__ bnsh, // [3][128]
                      _Float16* __restrict__ hs16,    // zero row NN in all 4 slices
                      int* __restrict__ cnt, unsigned short* __restrict__ csr_src)
{
    const int tid = blockIdx.x * blockDim.x + threadIdx.x;
    // part A: CSR pad fill + cnt zero (disjoint buffers, runs alongside part B)
    if (tid < ECAP / 8) {
        const unsigned int v = ((unsigned int)NN << 16) | (unsigned int)NN;
        uint4 q = {v, v, v, v};
        reinterpret_cast<uint4*>(csr_src)[tid] = q;
    } else if (tid < ECAP / 8 + NN) {
        cnt[tid - ECAP / 8] = 0;
    }
    // part B: original prep work
    if (tid < CONVT) {
        const int node = tid >> 5;
        const int c4 = tid & 31;
        const int c = c4 * 4;
        const int b = c >> 5;
        const int w = c & 31;
        const float4 v = reinterpret_cast<const float4*>(x)[tid];
        half4 o = {(_Float16)v.x, (_Float16)v.y, (_Float16)v.z, (_Float16)v.w};
        *reinterpret_cast<half4*>(xblk + (size_t)b * NPAD * 32 + (size_t)node * 32 + w) = o;
        return;
    }
    const int t2 = tid - CONVT;
    if (t2 < 12288) {
        const int layer = t2 >> 12;
        const int gl = (t2 >> 11) & 1;
        const int rem = t2 & 2047;
        const int lane = rem & 63;
        const int ks = (rem >> 6) & 3;
        const int n4 = rem >> 8;
        const float* W = (gl ? Wl : Wg) + (size_t)layer * HC * HC;
        const int kbase = ks * 32 + (lane >> 4) * 8;
        const int n = n4 * 16 + (lane & 15);
        _Float16* dst = wgl16 + (size_t)t2 * 8;
#pragma unroll
        for (int j = 0; j < 8; ++j) dst[j] = (_Float16)W[(size_t)(kbase + j) * HC + n];
    } else if (t2 < 13312) {
        const int f = t2 - 12288;
        const int lane = f & 63;
        const int ks = (f >> 6) & 3;
        const int n4 = f >> 8;
        const int kbase = ks * 32 + (lane >> 4) * 8;
        const int n = n4 * 16 + (lane & 15);
        _Float16* dst = wpp16 + (size_t)f * 8;
#pragma unroll
        for (int j = 0; j < 8; ++j) dst[j] = (_Float16)Wp[(size_t)(kbase + j) * OC + n];
    } else if (t2 < 13312 + NL * HC) {
        const int i = t2 - 13312;
        bsum[i] = bg[i] + bl[i];
        const float sc = bn_g[i] * rsqrtf(bn_rv[i] + BN_EPS);
        bnsc[i] = sc;
        bnsh[i] = bn_b[i] - bn_rm[i] * sc;
    } else if (t2 < 13312 + NL * HC + 128) {
        const int i = t2 - (13312 + NL * HC);
        const int slice = i >> 5;
        const int w = i & 31;
        hs16[(size_t)slice * NPAD * 32 + (size_t)NN * 32 + w] = (_Float16)0.f;
    }
}

// count + per-edge rank, 4 edges/thread (int4 load, ushort4 rank store)
__global__ void count_deg(const int* __restrict__ dst, int* __restrict__ cnt,
                          unsigned short* __restrict__ rank) {
    const int t = blockIdx.x * blockDim.x + threadIdx.x;
    if (t >= NE / 4) return;
    const int4 d4 = reinterpret_cast<const int4*>(dst)[t];
    ushort4v r;
    r[0] = (unsigned short)atomicAdd(&cnt[d4.x], 1);
    r[1] = (unsigned short)atomicAdd(&cnt[d4.y], 1);
    r[2] = (unsigned short)atomicAdd(&cnt[d4.z], 1);
    r[3] = (unsigned short)atomicAdd(&cnt[d4.w], 1);
    reinterpret_cast<ushort4v*>(rank)[t] = r;
}

// ---------------- exclusive scan over counts PADDED to multiple of 8; also dinv ----------------
__global__ __launch_bounds__(256) void scan1(const int* __restrict__ cnt,
                                             int* __restrict__ offs,
                                             int* __restrict__ partials,
                                             float* __restrict__ dinv) {
    __shared__ int sm[256];
    const int t = threadIdx.x;
    const int base = blockIdx.x * 1024 + t * 4;
    int c[4];
#pragma unroll
    for (int k = 0; k < 4; ++k) {
        int cv = 0;
        if (base + k < NN) {
            cv = cnt[base + k];
            dinv[base + k] = rsqrtf((float)(cv + 1));   // +1 self-loop
        }
        c[k] = (cv + 7) & ~7;   // pad to 8
    }
    int s = c[0] + c[1] + c[2] + c[3];
    sm[t] = s;
    __syncthreads();
    for (int off = 1; off < 256; off <<= 1) {
        int v = (t >= off) ? sm[t - off] : 0;
        __syncthreads();
        sm[t] += v;
        __syncthreads();
    }
    int run = sm[t] - s;
    if (t == 255) partials[blockIdx.x] = sm[255];
#pragma unroll
    for (int k = 0; k < 4; ++k) {
        if (base + k < NN) { offs[base + k] = run; run += c[k]; }
    }
}

// finalize offsets; per-block inline prefix of the 49 partials
__global__ __launch_bounds__(256) void scan3(int* __restrict__ offs, const int* __restrict__ partials) {
    __shared__ int sbase;
    const int K = blockIdx.x >> 2;            // == i>>10 for every i in this block
    if (threadIdx.x < 64) {
        const int l = threadIdx.x;
        int v = (l < K) ? partials[l] : 0;    // K <= 48 < NB
#pragma unroll
        for (int off = 32; off > 0; off >>= 1) v += __shfl_xor(v, off, 64);
        if (l == 0) sbase = v;
    }
    __syncthreads();
    const int i = blockIdx.x * blockDim.x + threadIdx.x;
    if (i < NN) offs[i] += sbase;
}

// ---------------- dual GEMM via MFMA + overlapped CSR fill (grid split) ----------------
__global__ __launch_bounds__(256) void gemm_dual_mfma(
    const _Float16* __restrict__ xblk,
    const _Float16* __restrict__ Wgp, const _Float16* __restrict__ Wlp,
    const float* __restrict__ bsum, const float* __restrict__ dinv,
    _Float16* __restrict__ hsblk, _Float16* __restrict__ preblk,
    const int* __restrict__ e_src, const int* __restrict__ e_dst,
    const int* __restrict__ offs, const unsigned short* __restrict__ rank,
    unsigned short* __restrict__ csr_src)
{
    if (blockIdx.x >= GEMMB) {
        // ---- CSR fill path (layer-0 launch only) ----
        const int e = (blockIdx.x - GEMMB) * 256 + threadIdx.x;
        if (e < NE) csr_src[offs[e_dst[e]] + (int)rank[e]] = (unsigned short)e_src[e];
        return;
    }

    __shared__ half8 sW[4096];       // [0,2048)=Wg, [2048,4096)=Wl — 64 KB
    const int t = threadIdx.x;
    {
        const half8* wg8 = reinterpret_cast<const half8*>(Wgp);
        const half8* wl8 = reinterpret_cast<const half8*>(Wlp);
#pragma unroll
        for (int ii = 0; ii < 8; ++ii) {
            sW[t + ii * 256] = wg8[t + ii * 256];
            sW[2048 + t + ii * 256] = wl8[t + ii * 256];
        }
    }
    const int wave = t >> 6;
    const int lane = t & 63;
    const int rowBase = blockIdx.x * 64 + wave * 16;
    const int ar = rowBase + (lane & 15);
    const int ak = (lane >> 4) * 8;

    half8 a[4];
#pragma unroll
    for (int ks = 0; ks < 4; ++ks)
        a[ks] = *reinterpret_cast<const half8*>(xblk + (size_t)ks * NPAD * 32 + (size_t)ar * 32 + ak);
    __syncthreads();

    f32x4 accG[8], accL[8];
#pragma unroll
    for (int n4 = 0; n4 < 8; ++n4) { accG[n4] = (f32x4)0.f; accL[n4] = (f32x4)0.f; }

#pragma unroll
    for (int n4 = 0; n4 < 8; ++n4) {
#pragma unroll
        for (int ks = 0; ks < 4; ++ks) {
            const half8 bG = sW[(n4 * 4 + ks) * 64 + lane];
            accG[n4] = __builtin_amdgcn_mfma_f32_16x16x32_f16(bG, a[ks], accG[n4], 0, 0, 0);
            const half8 bL = sW[2048 + (n4 * 4 + ks) * 64 + lane];
            accL[n4] = __builtin_amdgcn_mfma_f32_16x16x32_f16(bL, a[ks], accL[n4], 0, 0, 0);
        }
    }

    const int node = rowBase + (lane & 15);
    if (node >= NN) return;
    const int chq = (lane >> 4) * 4;       // channel offset within 16-tile
    const float dv = dinv[node];
    const float selfn = dv * dv;
#pragma unroll
    for (int n4 = 0; n4 < 8; ++n4) {
        const int ch = n4 * 16 + chq;      // 0..127, multiple of 4
        const int b = ch >> 5;
        const int w = ch & 31;
        const float4 bs = *reinterpret_cast<const float4*>(bsum + ch);
        const f32x4 hg = accG[n4];
        const f32x4 xl = accL[n4];
        half4 hsv, prv;
#pragma unroll
        for (int r = 0; r < 4; ++r) {
            const float hval = hg[r];
            hsv[r] = (_Float16)(dv * hval);
            prv[r] = (_Float16)(xl[r] + ((const float*)&bs)[r] + selfn * hval);
        }
        const size_t idx = (size_t)b * NPAD * 32 + (size_t)node * 32 + w;
        *reinterpret_cast<half4*>(hsblk + idx) = hsv;
        *reinterpret_cast<half4*>(preblk + idx) = prv;
    }
}

// ---------------- gather: 4 lanes/node x half8, 2-group unrolled (16 loads in flight) ----------------
#define ACCUM_TO(iv, A)                                                               \
    {                                                                                 \
        const _Float16* r0 = hb + (size_t)((iv).x & 0xffffu) * 32 + li * 8;           \
        const _Float16* r1 = hb + (size_t)((iv).x >> 16) * 32 + li * 8;               \
        const _Float16* r2 = hb + (size_t)((iv).y & 0xffffu) * 32 + li * 8;           \
        const _Float16* r3 = hb + (size_t)((iv).y >> 16) * 32 + li * 8;               \
        const _Float16* r4 = hb + (size_t)((iv).z & 0xffffu) * 32 + li * 8;           \
        const _Float16* r5 = hb + (size_t)((iv).z >> 16) * 32 + li * 8;               \
        const _Float16* r6 = hb + (size_t)((iv).w & 0xffffu) * 32 + li * 8;           \
        const _Float16* r7 = hb + (size_t)((iv).w >> 16) * 32 + li * 8;               \
        const half8 v0 = *reinterpret_cast<const half8*>(r0);                         \
        const half8 v1 = *reinterpret_cast<const half8*>(r1);                         \
        const half8 v2 = *reinterpret_cast<const half8*>(r2);                         \
        const half8 v3 = *reinterpret_cast<const half8*>(r3);                         \
        const half8 v4 = *reinterpret_cast<const half8*>(r4);                         \
        const half8 v5 = *reinterpret_cast<const half8*>(r5);                         \
        const half8 v6 = *reinterpret_cast<const half8*>(r6);                         \
        const half8 v7 = *reinterpret_cast<const half8*>(r7);                         \
        const half8 t01 = v0 + v1;                                                    \
        const half8 t23 = v2 + v3;                                                    \
        const half8 t45 = v4 + v5;                                                    \
        const half8 t67 = v6 + v7;                                                    \
        A += (t01 + t23) + (t45 + t67);                                               \
    }

__global__ __launch_bounds__(256) void gather_all(
    const unsigned short* __restrict__ csr_src, const int* __restrict__ offs,
    const int* __restrict__ cnt, const float* __restrict__ dinv,
    const _Float16* __restrict__ hs, const _Float16* __restrict__ pre,
    _Float16* __restrict__ xo,
    const float* __restrict__ sc, const float* __restrict__ sh)  // layer [128]
{
    const int bid = blockIdx.x;
    const int ps = (bid & 7) >> 1;                 // slice 0..3
    const int ib = (bid >> 3) * 2 + (bid & 1);     // within-slice block 0..781
    const _Float16* hb = hs + (size_t)ps * NPAD * 32;
    const _Float16* pb = pre + (size_t)ps * NPAD * 32;
    _Float16* xb = xo + (size_t)ps * NPAD * 32;

    const int node = ib * 64 + (threadIdx.x >> 2);
    if (node >= NN) return;
    const int li = threadIdx.x & 3;                // 4 lanes/node, 8 ch each
    const int ng = (cnt[node] + 7) >> 3;           // padded groups of 8
    const uint4* cp4 = reinterpret_cast<const uint4*>(csr_src + offs[node]);

    // hoisted epilogue loads: latency hides under the gather loop
    const float dv = dinv[node];
    const half8 pv = __builtin_nontemporal_load(
        reinterpret_cast<const half8*>(pb + (size_t)node * 32 + li * 8));
    const float4 scv0 = reinterpret_cast<const float4*>(sc + ps * 32 + li * 8)[0];
    const float4 scv1 = reinterpret_cast<const float4*>(sc + ps * 32 + li * 8)[1];
    const float4 shv0 = reinterpret_cast<const float4*>(sh + ps * 32 + li * 8)[0];
    const float4 shv1 = reinterpret_cast<const float4*>(sh + ps * 32 + li * 8)[1];

    half8 acc = {(_Float16)0.f, (_Float16)0.f, (_Float16)0.f, (_Float16)0.f,
                 (_Float16)0.f, (_Float16)0.f, (_Float16)0.f, (_Float16)0.f};
    half8 acc2 = acc;
    int g = 0;
    for (; g + 2 <= ng; g += 2) {
        const uint4 iva = cp4[g];
        const uint4 ivb = cp4[g + 1];
        ACCUM_TO(iva, acc)        // loads of both groups issue before either's
        ACCUM_TO(ivb, acc2)       // adds retire (independent accumulators)
    }
    if (g < ng) {
        const uint4 iv = cp4[g];
        ACCUM_TO(iv, acc)
    }
    acc += acc2;

    const float scs[8] = {scv0.x, scv0.y, scv0.z, scv0.w, scv1.x, scv1.y, scv1.z, scv1.w};
    const float shs[8] = {shv0.x, shv0.y, shv0.z, shv0.w, shv1.x, shv1.y, shv1.z, shv1.w};
    half8 o;
#pragma unroll
    for (int j = 0; j < 8; ++j)
        o[j] = (_Float16)fmaxf(((float)pv[j] + dv * (float)acc[j]) * scs[j] + shs[j], 0.f);
    __builtin_nontemporal_store(o, reinterpret_cast<half8*>(xb + (size_t)node * 32 + li * 8));
}

// ---------------- output projection via MFMA, LDS-staged weights, swapped operands ----------------
__global__ __launch_bounds__(256) void gemm_out_mfma(
    const _Float16* __restrict__ xblk, const _Float16* __restrict__ Wpp,
    const float* __restrict__ bp, float* __restrict__ out)
{
    __shared__ half8 sW[1024];       // 16 KB
    const int t = threadIdx.x;
    {
        const half8* wp8 = reinterpret_cast<const half8*>(Wpp);
#pragma unroll
        for (int ii = 0; ii < 4; ++ii) sW[t + ii * 256] = wp8[t + ii * 256];
    }
    const int wave = t >> 6;
    const int lane = t & 63;
    const int rowBase = blockIdx.x * 64 + wave * 16;
    const int ar = rowBase + (lane & 15);
    const int ak = (lane >> 4) * 8;

    half8 a[4];
#pragma unroll
    for (int ks = 0; ks < 4; ++ks)
        a[ks] = *reinterpret_cast<const half8*>(xblk + (size_t)ks * NPAD * 32 + (size_t)ar * 32 + ak);
    __syncthreads();

    f32x4 acc[4];
#pragma unroll
    for (int n4 = 0; n4 < 4; ++n4) acc[n4] = (f32x4)0.f;

#pragma unroll
    for (int n4 = 0; n4 < 4; ++n4)
#pragma unroll
        for (int ks = 0; ks < 4; ++ks)
            acc[n4] = __builtin_amdgcn_mfma_f32_16x16x32_f16(sW[(n4 * 4 + ks) * 64 + lane], a[ks], acc[n4], 0, 0, 0);

    const int node = rowBase + (lane & 15);
    if (node >= NN) return;
    const int chq = (lane >> 4) * 4;
#pragma unroll
    for (int n4 = 0; n4 < 4; ++n4) {
        const int ch = n4 * 16 + chq;
        const float4 bp4 = *reinterpret_cast<const float4*>(bp + ch);
        float4 o;
        o.x = acc[n4][0] + bp4.x;
        o.y = acc[n4][1] + bp4.y;
        o.z = acc[n4][2] + bp4.z;
        o.w = acc[n4][3] + bp4.w;
        *reinterpret_cast<float4*>(out + (size_t)node * OC + ch) = o;
    }
}

extern "C" void kernel_launch(void* const* d_in, const int* in_sizes, int n_in,
                              void* d_out, int out_size, void* d_ws, size_t ws_size,
                              hipStream_t stream) {
    const float* x    = (const float*)d_in[0];
    const int*   ei   = (const int*)d_in[1];
    const float* Wg   = (const float*)d_in[2];
    const float* bg   = (const float*)d_in[3];
    const float* Wl   = (const float*)d_in[4];
    const float* bl   = (const float*)d_in[5];
    const float* bn_g = (const float*)d_in[6];
    const float* bn_b = (const float*)d_in[7];
    const float* bn_rm= (const float*)d_in[8];
    const float* bn_rv= (const float*)d_in[9];
    const float* Wp   = (const float*)d_in[10];
    const float* bp   = (const float*)d_in[11];
    float* out = (float*)d_out;

    const int* e_src = ei;
    const int* e_dst = ei + NE;

    // workspace layout
    char* p = (char*)d_ws;
    _Float16* x16a = (_Float16*)p;            p += (size_t)NPAD * HC * 2;   // blocked [4][NPAD][32]
    _Float16* x16b = (_Float16*)p;            p += (size_t)NPAD * HC * 2;
    _Float16* hs16 = (_Float16*)p;            p += (size_t)NPAD * HC * 2;
    _Float16* pre16= (_Float16*)p;            p += (size_t)NPAD * HC * 2;
    float* dinv    = (float*)p;               p += (size_t)(NN + 8) * 4;
    unsigned short* csr_src = (unsigned short*)p;  p += (size_t)ECAP * 2;
    unsigned short* rank    = (unsigned short*)p;  p += (size_t)NE * 2;
    int* cnt       = (int*)p;                 p += (size_t)NN * 4;
    int* offs      = (int*)p;                 p += (size_t)(NN + 8) * 4;
    int* partials  = (int*)p;                 p += (size_t)NB * 4 + 64;
    _Float16* wgl16 = (_Float16*)p;           p += (size_t)12288 * 8 * 2;
    _Float16* wpp16 = (_Float16*)p;           p += (size_t)1024 * 8 * 2;
    float* bsum    = (float*)p;               p += (size_t)NL * HC * 4;
    float* bnsc    = (float*)p;               p += (size_t)NL * HC * 4;
    float* bnsh    = (float*)p;               p += (size_t)NL * HC * 4;

    const int nblk = (NN + 255) / 256;

    prep0<<<(CONVT + 16384 + 255) / 256, 256, 0, stream>>>(
        x, x16a, Wg, Wl, Wp, bg, bl, bn_g, bn_b, bn_rm, bn_rv,
        wgl16, wpp16, bsum, bnsc, bnsh, hs16, cnt, csr_src);
    count_deg<<<(NE / 4 + 255) / 256, 256, 0, stream>>>(e_dst, cnt, rank);
    scan1<<<NB, 256, 0, stream>>>(cnt, offs, partials, dinv);
    scan3<<<nblk, 256, 0, stream>>>(offs, partials);

    const int gat_blocks = 8 * 391;          // 3128: (slice, 64-node block) coverage

    _Float16* xin16 = x16a;
    _Float16* pp16[NL] = {x16b, x16a, x16b};
    for (int l = 0; l < NL; ++l) {
        _Float16* xnext16 = pp16[l];
        // layer 0: GEMM blocks + overlapped CSR-fill blocks in one dispatch
        const int grid = (l == 0) ? (GEMMB + EBLK) : GEMMB;
        gemm_dual_mfma<<<grid, 256, 0, stream>>>(
            xin16,
            wgl16 + (size_t)(l * 2 + 0) * 2048 * 8,
            wgl16 + (size_t)(l * 2 + 1) * 2048 * 8,
            bsum + (size_t)l * HC, dinv, hs16, pre16,
            e_src, e_dst, offs, rank, csr_src);
        gather_all<<<gat_blocks, 256, 0, stream>>>(
            csr_src, offs, cnt, dinv, hs16, pre16, xnext16,
            bnsc + (size_t)l * HC, bnsh + (size_t)l * HC);
        xin16 = xnext16;
    }

    gemm_out_mfma<<<GEMMB, 256, 0, stream>>>(xin16, wpp16, bp, out);
}

// Round 21
// 177.326 us; speedup vs baseline: 1.0288x; 1.0288x over previous
//
#include <hip/hip_runtime.h>
#include <cstddef>

#define NN 50000
#define NPAD 50048            // 782 blocks * 64 rows
#define NE 800000
#define HC 128
#define OC 64
#define NL 3
#define BN_EPS 1e-5f
#define NB ((NN + 1023) / 1024)
#define CONVT (NN * 32)       // conv threads in prep0
#define ECAP 1250000          // padded CSR capacity (NE + 8*NN > upper bound), mult of 8
#define GEMMB 782             // gemm blocks (NPAD/64)
#define EBLK 3125             // edge blocks (NE/256)

typedef _Float16 half8 __attribute__((ext_vector_type(8)));
typedef _Float16 half4 __attribute__((ext_vector_type(4)));
typedef float f32x4 __attribute__((ext_vector_type(4)));
typedef unsigned short ushort4v __attribute__((ext_vector_type(4)));

// ---------------- prep0: csr pad fill + cnt zero + x conv + weight pack + BN fold + zero-row ----------------
__global__ void prep0(const float* __restrict__ x, _Float16* __restrict__ xblk,
                      const float* __restrict__ Wg, const float* __restrict__ Wl,
                      const float* __restrict__ Wp,
                      const float* __restrict__ bg, const float* __restrict__ bl,
                      const float* __restrict__ bn_g, const float* __restrict__ bn_b,
                      const float* __restrict__ bn_rm, const float* __restrict__ bn_rv,
                      _Float16* __restrict__ wgl16,   // [3][2][2048][8]
                      _Float16* __restrict__ wpp16,   // [1024][8]
                      float* __restrict__ bsum,       // [3][128]
                      float* __restrict__ bnsc, float* __restrict__ bnsh, // [3][128]
                      _Float16* __restrict__ hs16,    // zero row NN in all 4 slices
                      int* __restrict__ cnt, unsigned short* __restrict__ csr_src)
{
    const int tid = blockIdx.x * blockDim.x + threadIdx.x;
    // part A: CSR pad fill + cnt zero (disjoint buffers, runs alongside part B)
    if (tid < ECAP / 8) {
        const unsigned int v = ((unsigned int)NN << 16) | (unsigned int)NN;
        uint4 q = {v, v, v, v};
        reinterpret_cast<uint4*>(csr_src)[tid] = q;
    } else if (tid < ECAP / 8 + NN) {
        cnt[tid - ECAP / 8] = 0;
    }
    // part B: original prep work
    if (tid < CONVT) {
        const int node = tid >> 5;
        const int c4 = tid & 31;
        const int c = c4 * 4;
        const int b = c >> 5;
        const int w = c & 31;
        const float4 v = reinterpret_cast<const float4*>(x)[tid];
        half4 o = {(_Float16)v.x, (_Float16)v.y, (_Float16)v.z, (_Float16)v.w};
        *reinterpret_cast<half4*>(xblk + (size_t)b * NPAD * 32 + (size_t)node * 32 + w) = o;
        return;
    }
    const int t2 = tid - CONVT;
    if (t2 < 12288) {
        const int layer = t2 >> 12;
        const int gl = (t2 >> 11) & 1;
        const int rem = t2 & 2047;
        const int lane = rem & 63;
        const int ks = (rem >> 6) & 3;
        const int n4 = rem >> 8;
        const float* W = (gl ? Wl : Wg) + (size_t)layer * HC * HC;
        const int kbase = ks * 32 + (lane >> 4) * 8;
        const int n = n4 * 16 + (lane & 15);
        _Float16* dst = wgl16 + (size_t)t2 * 8;
#pragma unroll
        for (int j = 0; j < 8; ++j) dst[j] = (_Float16)W[(size_t)(kbase + j) * HC + n];
    } else if (t2 < 13312) {
        const int f = t2 - 12288;
        const int lane = f & 63;
        const int ks = (f >> 6) & 3;
        const int n4 = f >> 8;
        const int kbase = ks * 32 + (lane >> 4) * 8;
        const int n = n4 * 16 + (lane & 15);
        _Float16* dst = wpp16 + (size_t)f * 8;
#pragma unroll
        for (int j = 0; j < 8; ++j) dst[j] = (_Float16)Wp[(size_t)(kbase + j) * OC + n];
    } else if (t2 < 13312 + NL * HC) {
        const int i = t2 - 13312;
        bsum[i] = bg[i] + bl[i];
        const float sc = bn_g[i] * rsqrtf(bn_rv[i] + BN_EPS);
        bnsc[i] = sc;
        bnsh[i] = bn_b[i] - bn_rm[i] * sc;
    } else if (t2 < 13312 + NL * HC + 128) {
        const int i = t2 - (13312 + NL * HC);
        const int slice = i >> 5;
        const int w = i & 31;
        hs16[(size_t)slice * NPAD * 32 + (size_t)NN * 32 + w] = (_Float16)0.f;
    }
}

// count + per-edge rank, 4 edges/thread (int4 load, ushort4 rank store)
__global__ void count_deg(const int* __restrict__ dst, int* __restrict__ cnt,
                          unsigned short* __restrict__ rank) {
    const int t = blockIdx.x * blockDim.x + threadIdx.x;
    if (t >= NE / 4) return;
    const int4 d4 = reinterpret_cast<const int4*>(dst)[t];
    ushort4v r;
    r[0] = (unsigned short)atomicAdd(&cnt[d4.x], 1);
    r[1] = (unsigned short)atomicAdd(&cnt[d4.y], 1);
    r[2] = (unsigned short)atomicAdd(&cnt[d4.z], 1);
    r[3] = (unsigned short)atomicAdd(&cnt[d4.w], 1);
    reinterpret_cast<ushort4v*>(rank)[t] = r;
}

// ---------------- exclusive scan over counts PADDED to multiple of 8; also dinv ----------------
__global__ __launch_bounds__(256) void scan1(const int* __restrict__ cnt,
                                             int* __restrict__ offs,
                                             int* __restrict__ partials,
                                             float* __restrict__ dinv) {
    __shared__ int sm[256];
    const int t = threadIdx.x;
    const int base = blockIdx.x * 1024 + t * 4;
    int c[4];
#pragma unroll
    for (int k = 0; k < 4; ++k) {
        int cv = 0;
        if (base + k < NN) {
            cv = cnt[base + k];
            dinv[base + k] = rsqrtf((float)(cv + 1));   // +1 self-loop
        }
        c[k] = (cv + 7) & ~7;   // pad to 8
    }
    int s = c[0] + c[1] + c[2] + c[3];
    sm[t] = s;
    __syncthreads();
    for (int off = 1; off < 256; off <<= 1) {
        int v = (t >= off) ? sm[t - off] : 0;
        __syncthreads();
        sm[t] += v;
        __syncthreads();
    }
    int run = sm[t] - s;
    if (t == 255) partials[blockIdx.x] = sm[255];
#pragma unroll
    for (int k = 0; k < 4; ++k) {
        if (base + k < NN) { offs[base + k] = run; run += c[k]; }
    }
}

// finalize offsets; per-block inline prefix of the 49 partials
__global__ __launch_bounds__(256) void scan3(int* __restrict__ offs, const int* __restrict__ partials) {
    __shared__ int sbase;
    const int K = blockIdx.x >> 2;            // == i>>10 for every i in this block
    if (threadIdx.x < 64) {
        const int l = threadIdx.x;
        int v = (l < K) ? partials[l] : 0;    // K <= 48 < NB
#pragma unroll
        for (int off = 32; off > 0; off >>= 1) v += __shfl_xor(v, off, 64);
        if (l == 0) sbase = v;
    }
    __syncthreads();
    const int i = blockIdx.x * blockDim.x + threadIdx.x;
    if (i < NN) offs[i] += sbase;
}

// ---------------- dual GEMM via MFMA + overlapped CSR fill (grid split) ----------------
// Blocks [0,GEMMB): GEMM with LDS-staged weights. Blocks [GEMMB, ...): edge scatter
// (csr fill) — independent work overlapped under the GEMM's compute.
__global__ __launch_bounds__(256) void gemm_dual_mfma(
    const _Float16* __restrict__ xblk,
    const _Float16* __restrict__ Wgp, const _Float16* __restrict__ Wlp,
    const float* __restrict__ bsum, const float* __restrict__ dinv,
    _Float16* __restrict__ hsblk, _Float16* __restrict__ preblk,
    const int* __restrict__ e_src, const int* __restrict__ e_dst,
    const int* __restrict__ offs, const unsigned short* __restrict__ rank,
    unsigned short* __restrict__ csr_src)
{
    if (blockIdx.x >= GEMMB) {
        // ---- CSR fill path (layer-0 launch only) ----
        const int e = (blockIdx.x - GEMMB) * 256 + threadIdx.x;
        if (e < NE) csr_src[offs[e_dst[e]] + (int)rank[e]] = (unsigned short)e_src[e];
        return;
    }

    __shared__ half8 sW[4096];       // [0,2048)=Wg, [2048,4096)=Wl — 64 KB
    const int t = threadIdx.x;
    {
        const half8* wg8 = reinterpret_cast<const half8*>(Wgp);
        const half8* wl8 = reinterpret_cast<const half8*>(Wlp);
#pragma unroll
        for (int ii = 0; ii < 8; ++ii) {
            sW[t + ii * 256] = wg8[t + ii * 256];
            sW[2048 + t + ii * 256] = wl8[t + ii * 256];
        }
    }
    const int wave = t >> 6;
    const int lane = t & 63;
    const int rowBase = blockIdx.x * 64 + wave * 16;
    const int ar = rowBase + (lane & 15);
    const int ak = (lane >> 4) * 8;

    half8 a[4];
#pragma unroll
    for (int ks = 0; ks < 4; ++ks)
        a[ks] = *reinterpret_cast<const half8*>(xblk + (size_t)ks * NPAD * 32 + (size_t)ar * 32 + ak);
    __syncthreads();

    f32x4 accG[8], accL[8];
#pragma unroll
    for (int n4 = 0; n4 < 8; ++n4) { accG[n4] = (f32x4)0.f; accL[n4] = (f32x4)0.f; }

#pragma unroll
    for (int n4 = 0; n4 < 8; ++n4) {
#pragma unroll
        for (int ks = 0; ks < 4; ++ks) {
            const half8 bG = sW[(n4 * 4 + ks) * 64 + lane];
            accG[n4] = __builtin_amdgcn_mfma_f32_16x16x32_f16(bG, a[ks], accG[n4], 0, 0, 0);
            const half8 bL = sW[2048 + (n4 * 4 + ks) * 64 + lane];
            accL[n4] = __builtin_amdgcn_mfma_f32_16x16x32_f16(bL, a[ks], accL[n4], 0, 0, 0);
        }
    }

    const int node = rowBase + (lane & 15);
    if (node >= NN) return;
    const int chq = (lane >> 4) * 4;       // channel offset within 16-tile
    const float dv = dinv[node];
    const float selfn = dv * dv;
#pragma unroll
    for (int n4 = 0; n4 < 8; ++n4) {
        const int ch = n4 * 16 + chq;      // 0..127, multiple of 4
        const int b = ch >> 5;
        const int w = ch & 31;
        const float4 bs = *reinterpret_cast<const float4*>(bsum + ch);
        const f32x4 hg = accG[n4];
        const f32x4 xl = accL[n4];
        half4 hsv, prv;
#pragma unroll
        for (int r = 0; r < 4; ++r) {
            const float hval = hg[r];
            hsv[r] = (_Float16)(dv * hval);
            prv[r] = (_Float16)(xl[r] + ((const float*)&bs)[r] + selfn * hval);
        }
        const size_t idx = (size_t)b * NPAD * 32 + (size_t)node * 32 + w;
        *reinterpret_cast<half4*>(hsblk + idx) = hsv;
        *reinterpret_cast<half4*>(preblk + idx) = prv;
    }
}

// ---------------- gather: 4 lanes/node x half8, padded CSR, pk-fp16 tree, XCD-pinned slices ----------------
#define ACCUM(iv)                                                                     \
    {                                                                                 \
        const _Float16* r0 = hb + (size_t)((iv).x & 0xffffu) * 32 + li * 8;           \
        const _Float16* r1 = hb + (size_t)((iv).x >> 16) * 32 + li * 8;               \
        const _Float16* r2 = hb + (size_t)((iv).y & 0xffffu) * 32 + li * 8;           \
        const _Float16* r3 = hb + (size_t)((iv).y >> 16) * 32 + li * 8;               \
        const _Float16* r4 = hb + (size_t)((iv).z & 0xffffu) * 32 + li * 8;           \
        const _Float16* r5 = hb + (size_t)((iv).z >> 16) * 32 + li * 8;               \
        const _Float16* r6 = hb + (size_t)((iv).w & 0xffffu) * 32 + li * 8;           \
        const _Float16* r7 = hb + (size_t)((iv).w >> 16) * 32 + li * 8;               \
        const half8 v0 = *reinterpret_cast<const half8*>(r0);                         \
        const half8 v1 = *reinterpret_cast<const half8*>(r1);                         \
        const half8 v2 = *reinterpret_cast<const half8*>(r2);                         \
        const half8 v3 = *reinterpret_cast<const half8*>(r3);                         \
        const half8 v4 = *reinterpret_cast<const half8*>(r4);                         \
        const half8 v5 = *reinterpret_cast<const half8*>(r5);                         \
        const half8 v6 = *reinterpret_cast<const half8*>(r6);                         \
        const half8 t01 = v0 + v1;                                                    \
        const half8 t23 = v2 + v3;                                                    \
        const half8 v7 = *reinterpret_cast<const half8*>(r7);                         \
        const half8 t45 = v4 + v5;                                                    \
        const half8 t67 = v6 + v7;                                                    \
        acc += (t01 + t23) + (t45 + t67);                                             \
    }

__global__ __launch_bounds__(256) void gather_all(
    const unsigned short* __restrict__ csr_src, const int* __restrict__ offs,
    const int* __restrict__ cnt, const float* __restrict__ dinv,
    const _Float16* __restrict__ hs, const _Float16* __restrict__ pre,
    _Float16* __restrict__ xo,
    const float* __restrict__ sc, const float* __restrict__ sh)  // layer [128]
{
    const int bid = blockIdx.x;
    const int ps = (bid & 7) >> 1;                 // slice 0..3
    const int ib = (bid >> 3) * 2 + (bid & 1);     // within-slice block 0..781
    const _Float16* hb = hs + (size_t)ps * NPAD * 32;
    const _Float16* pb = pre + (size_t)ps * NPAD * 32;
    _Float16* xb = xo + (size_t)ps * NPAD * 32;

    const int node = ib * 64 + (threadIdx.x >> 2);
    if (node >= NN) return;
    const int li = threadIdx.x & 3;                // 4 lanes/node, 8 ch each
    const int ng = (cnt[node] + 7) >> 3;           // padded groups of 8
    const uint4* cp4 = reinterpret_cast<const uint4*>(csr_src + offs[node]);

    // hoisted epilogue loads: latency hides under the gather loop
    const float dv = dinv[node];
    const half8 pv = __builtin_nontemporal_load(
        reinterpret_cast<const half8*>(pb + (size_t)node * 32 + li * 8));
    const float4 scv0 = reinterpret_cast<const float4*>(sc + ps * 32 + li * 8)[0];
    const float4 scv1 = reinterpret_cast<const float4*>(sc + ps * 32 + li * 8)[1];
    const float4 shv0 = reinterpret_cast<const float4*>(sh + ps * 32 + li * 8)[0];
    const float4 shv1 = reinterpret_cast<const float4*>(sh + ps * 32 + li * 8)[1];

    half8 acc = {(_Float16)0.f, (_Float16)0.f, (_Float16)0.f, (_Float16)0.f,
                 (_Float16)0.f, (_Float16)0.f, (_Float16)0.f, (_Float16)0.f};
    if (ng > 0) {
        uint4 iv = cp4[0];
        for (int g = 1; g < ng; ++g) {
            const uint4 nx = cp4[g];   // prefetch next index chunk
            ACCUM(iv)
            iv = nx;
        }
        ACCUM(iv)
    }

    const float scs[8] = {scv0.x, scv0.y, scv0.z, scv0.w, scv1.x, scv1.y, scv1.z, scv1.w};
    const float shs[8] = {shv0.x, shv0.y, shv0.z, shv0.w, shv1.x, shv1.y, shv1.z, shv1.w};
    half8 o;
#pragma unroll
    for (int j = 0; j < 8; ++j)
        o[j] = (_Float16)fmaxf(((float)pv[j] + dv * (float)acc[j]) * scs[j] + shs[j], 0.f);
    __builtin_nontemporal_store(o, reinterpret_cast<half8*>(xb + (size_t)node * 32 + li * 8));
}

// ---------------- output projection via MFMA, LDS-staged weights, swapped operands ----------------
__global__ __launch_bounds__(256) void gemm_out_mfma(
    const _Float16* __restrict__ xblk, const _Float16* __restrict__ Wpp,
    const float* __restrict__ bp, float* __restrict__ out)
{
    __shared__ half8 sW[1024];       // 16 KB
    const int t = threadIdx.x;
    {
        const half8* wp8 = reinterpret_cast<const half8*>(Wpp);
#pragma unroll
        for (int ii = 0; ii < 4; ++ii) sW[t + ii * 256] = wp8[t + ii * 256];
    }
    const int wave = t >> 6;
    const int lane = t & 63;
    const int rowBase = blockIdx.x * 64 + wave * 16;
    const int ar = rowBase + (lane & 15);
    const int ak = (lane >> 4) * 8;

    half8 a[4];
#pragma unroll
    for (int ks = 0; ks < 4; ++ks)
        a[ks] = *reinterpret_cast<const half8*>(xblk + (size_t)ks * NPAD * 32 + (size_t)ar * 32 + ak);
    __syncthreads();

    f32x4 acc[4];
#pragma unroll
    for (int n4 = 0; n4 < 4; ++n4) acc[n4] = (f32x4)0.f;

#pragma unroll
    for (int n4 = 0; n4 < 4; ++n4)
#pragma unroll
        for (int ks = 0; ks < 4; ++ks)
            acc[n4] = __builtin_amdgcn_mfma_f32_16x16x32_f16(sW[(n4 * 4 + ks) * 64 + lane], a[ks], acc[n4], 0, 0, 0);

    const int node = rowBase + (lane & 15);
    if (node >= NN) return;
    const int chq = (lane >> 4) * 4;
#pragma unroll
    for (int n4 = 0; n4 < 4; ++n4) {
        const int ch = n4 * 16 + chq;
        const float4 bp4 = *reinterpret_cast<const float4*>(bp + ch);
        float4 o;
        o.x = acc[n4][0] + bp4.x;
        o.y = acc[n4][1] + bp4.y;
        o.z = acc[n4][2] + bp4.z;
        o.w = acc[n4][3] + bp4.w;
        *reinterpret_cast<float4*>(out + (size_t)node * OC + ch) = o;
    }
}

extern "C" void kernel_launch(void* const* d_in, const int* in_sizes, int n_in,
                              void* d_out, int out_size, void* d_ws, size_t ws_size,
                              hipStream_t stream) {
    const float* x    = (const float*)d_in[0];
    const int*   ei   = (const int*)d_in[1];
    const float* Wg   = (const float*)d_in[2];
    const float* bg   = (const float*)d_in[3];
    const float* Wl   = (const float*)d_in[4];
    const float* bl   = (const float*)d_in[5];
    const float* bn_g = (const float*)d_in[6];
    const float* bn_b = (const float*)d_in[7];
    const float* bn_rm= (const float*)d_in[8];
    const float* bn_rv= (const float*)d_in[9];
    const float* Wp   = (const float*)d_in[10];
    const float* bp   = (const float*)d_in[11];
    float* out = (float*)d_out;

    const int* e_src = ei;
    const int* e_dst = ei + NE;

    // workspace layout
    char* p = (char*)d_ws;
    _Float16* x16a = (_Float16*)p;            p += (size_t)NPAD * HC * 2;   // blocked [4][NPAD][32]
    _Float16* x16b = (_Float16*)p;            p += (size_t)NPAD * HC * 2;
    _Float16* hs16 = (_Float16*)p;            p += (size_t)NPAD * HC * 2;
    _Float16* pre16= (_Float16*)p;            p += (size_t)NPAD * HC * 2;
    float* dinv    = (float*)p;               p += (size_t)(NN + 8) * 4;
    unsigned short* csr_src = (unsigned short*)p;  p += (size_t)ECAP * 2;
    unsigned short* rank    = (unsigned short*)p;  p += (size_t)NE * 2;
    int* cnt       = (int*)p;                 p += (size_t)NN * 4;
    int* offs      = (int*)p;                 p += (size_t)(NN + 8) * 4;
    int* partials  = (int*)p;                 p += (size_t)NB * 4 + 64;
    _Float16* wgl16 = (_Float16*)p;           p += (size_t)12288 * 8 * 2;
    _Float16* wpp16 = (_Float16*)p;           p += (size_t)1024 * 8 * 2;
    float* bsum    = (float*)p;               p += (size_t)NL * HC * 4;
    float* bnsc    = (float*)p;               p += (size_t)NL * HC * 4;
    float* bnsh    = (float*)p;               p += (size_t)NL * HC * 4;

    const int nblk = (NN + 255) / 256;

    prep0<<<(CONVT + 16384 + 255) / 256, 256, 0, stream>>>(
        x, x16a, Wg, Wl, Wp, bg, bl, bn_g, bn_b, bn_rm, bn_rv,
        wgl16, wpp16, bsum, bnsc, bnsh, hs16, cnt, csr_src);
    count_deg<<<(NE / 4 + 255) / 256, 256, 0, stream>>>(e_dst, cnt, rank);
    scan1<<<NB, 256, 0, stream>>>(cnt, offs, partials, dinv);
    scan3<<<nblk, 256, 0, stream>>>(offs, partials);

    const int gat_blocks = 8 * 391;          // 3128: (slice, 64-node block) coverage

    _Float16* xin16 = x16a;
    _Float16* pp16[NL] = {x16b, x16a, x16b};
    for (int l = 0; l < NL; ++l) {
        _Float16* xnext16 = pp16[l];
        // layer 0: GEMM blocks + overlapped CSR-fill blocks in one dispatch
        const int grid = (l == 0) ? (GEMMB + EBLK) : GEMMB;
        gemm_dual_mfma<<<grid, 256, 0, stream>>>(
            xin16,
            wgl16 + (size_t)(l * 2 + 0) * 2048 * 8,
            wgl16 + (size_t)(l * 2 + 1) * 2048 * 8,
            bsum + (size_t)l * HC, dinv, hs16, pre16,
            e_src, e_dst, offs, rank, csr_src);
        gather_all<<<gat_blocks, 256, 0, stream>>>(
            csr_src, offs, cnt, dinv, hs16, pre16, xnext16,
            bnsc + (size_t)l * HC, bnsh + (size_t)l * HC);
        xin16 = xnext16;
    }

    gemm_out_mfma<<<GEMMB, 256, 0, stream>>>(xin16, wpp16, bp, out);
}